// Round 1
// baseline (44.704 us; speedup 1.0000x reference)
//
#include <hip/hip_runtime.h>

// Problem constants (from reference): X is [B=4, S=4096, D=2048] float32.
#define PE_B 4
#define PE_S 4096
#define PE_D 2048

// Each thread owns one float4 chunk at (s, d0) covering 2 (sin,cos) pairs,
// computes the PE values once, then loops over the batch dim (4 iters).
// Trig cost amortized 8 output floats per sincos pair-set; memory path is
// coalesced float4 (16B/lane).
__global__ __launch_bounds__(256) void
PositionalEncodingLayer_44633300140770_kernel(const float* __restrict__ X,
                                              float* __restrict__ out) {
    const int t = blockIdx.x * blockDim.x + threadIdx.x;
    // chunks per row = D/4 = 512
    const int s  = t >> 9;          // t / 512
    const int c  = t & 511;         // t % 512
    const int d0 = c << 2;          // starting d index (multiple of 4)

    if (s >= PE_S) return;

    // pair indices i0 = d0/2, i1 = d0/2 + 1
    const float log2_10000 = 13.287712379549449f;
    const float pos = (float)s;
    const float i0 = (float)(d0 >> 1);
    const float i1 = i0 + 1.0f;

    // inv_freq = 10000^(-2i/D) = exp2(-(2i/D)*log2(10000))
    const float inv_f0 = exp2f(-(2.0f * i0 / (float)PE_D) * log2_10000);
    const float inv_f1 = exp2f(-(2.0f * i1 / (float)PE_D) * log2_10000);

    float s0, c0, s1, c1;
    sincosf(pos * inv_f0, &s0, &c0);
    sincosf(pos * inv_f1, &s1, &c1);

    float4 pe;
    pe.x = s0; pe.y = c0; pe.z = s1; pe.w = c1;

    // float4 view: row s starts at element s*D; chunk c at s*D/4 + c in float4 units
    const float4* __restrict__ X4 = (const float4*)X;
    float4* __restrict__ O4 = (float4*)out;

    const size_t row_chunk = (size_t)s * (PE_D / 4) + (size_t)c;
    const size_t batch_stride = (size_t)PE_S * (PE_D / 4);  // float4 units per batch

#pragma unroll
    for (int b = 0; b < PE_B; ++b) {
        const size_t idx = (size_t)b * batch_stride + row_chunk;
        float4 x = X4[idx];
        x.x += pe.x; x.y += pe.y; x.z += pe.z; x.w += pe.w;
        O4[idx] = x;
    }
}

extern "C" void kernel_launch(void* const* d_in, const int* in_sizes, int n_in,
                              void* d_out, int out_size, void* d_ws, size_t ws_size,
                              hipStream_t stream) {
    (void)in_sizes; (void)n_in; (void)d_ws; (void)ws_size; (void)out_size;
    const float* X = (const float*)d_in[0];
    float* out = (float*)d_out;

    const int total_threads = PE_S * (PE_D / 4);   // 4096 * 512 = 2,097,152
    const int block = 256;
    const int grid = (total_threads + block - 1) / block;  // 8192 blocks

    PositionalEncodingLayer_44633300140770_kernel<<<grid, block, 0, stream>>>(X, out);
}

// Round 3
// 44.121 us; speedup vs baseline: 1.0132x; 1.0132x over previous
//
#include <hip/hip_runtime.h>

// Problem constants (from reference): X is [B=4, S=4096, D=2048] float32.
#define PE_B 4
#define PE_S 4096
#define PE_D 2048

// Native clang vector type — __builtin_nontemporal_store requires a
// scalar/native-vector pointee (HIP_vector_type float4 is rejected).
typedef float f32x4 __attribute__((ext_vector_type(4)));

// Each thread owns one float4 chunk at (s, d0) covering 2 (sin,cos) pairs,
// computes the PE values once, then loops over the batch dim (4 iters).
// Output stores are NONTEMPORAL: out is never re-read, so bypassing L2/L3
// keeps the full 256MB Infinity Cache available for X (128MB) -> X stays
// L3-resident across graph replays and HBM read traffic drops to ~0.
__global__ __launch_bounds__(256) void
PositionalEncodingLayer_44633300140770_kernel(const float* __restrict__ X,
                                              float* __restrict__ out) {
    const int t = blockIdx.x * blockDim.x + threadIdx.x;
    // chunks per row = D/4 = 512
    const int s  = t >> 9;          // t / 512
    const int c  = t & 511;         // t % 512
    const int d0 = c << 2;          // starting d index (multiple of 4)

    if (s >= PE_S) return;

    // pair indices i0 = d0/2, i1 = d0/2 + 1
    const float log2_10000 = 13.287712379549449f;
    const float pos = (float)s;
    const float i0 = (float)(d0 >> 1);
    const float i1 = i0 + 1.0f;

    // inv_freq = 10000^(-2i/D) = exp2(-(2i/D)*log2(10000))
    const float inv_f0 = exp2f(-(2.0f * i0 / (float)PE_D) * log2_10000);
    const float inv_f1 = exp2f(-(2.0f * i1 / (float)PE_D) * log2_10000);

    float s0, c0, s1, c1;
    sincosf(pos * inv_f0, &s0, &c0);
    sincosf(pos * inv_f1, &s1, &c1);

    f32x4 pe;
    pe.x = s0; pe.y = c0; pe.z = s1; pe.w = c1;

    const f32x4* __restrict__ X4 = (const f32x4*)X;
    f32x4* __restrict__ O4 = (f32x4*)out;

    const size_t row_chunk = (size_t)s * (PE_D / 4) + (size_t)c;
    const size_t batch_stride = (size_t)PE_S * (PE_D / 4);  // f32x4 units per batch

#pragma unroll
    for (int b = 0; b < PE_B; ++b) {
        const size_t idx = (size_t)b * batch_stride + row_chunk;
        f32x4 x = X4[idx];
        x += pe;
        __builtin_nontemporal_store(x, &O4[idx]);
    }
}

extern "C" void kernel_launch(void* const* d_in, const int* in_sizes, int n_in,
                              void* d_out, int out_size, void* d_ws, size_t ws_size,
                              hipStream_t stream) {
    (void)in_sizes; (void)n_in; (void)d_ws; (void)ws_size; (void)out_size;
    const float* X = (const float*)d_in[0];
    float* out = (float*)d_out;

    const int total_threads = PE_S * (PE_D / 4);   // 4096 * 512 = 2,097,152
    const int block = 256;
    const int grid = (total_threads + block - 1) / block;  // 8192 blocks

    PositionalEncodingLayer_44633300140770_kernel<<<grid, block, 0, stream>>>(X, out);
}

// Round 4
// 43.037 us; speedup vs baseline: 1.0387x; 1.0252x over previous
//
#include <hip/hip_runtime.h>

// Problem constants (from reference): X is [B=4, S=4096, D=2048] float32.
#define PE_B 4
#define PE_S 4096
#define PE_D 2048

// Native clang vector type (16B load/store units).
typedef float f32x4 __attribute__((ext_vector_type(4)));

// Each thread owns one float4 chunk at (s, d0) covering 2 (sin,cos) pairs,
// computes the PE values once, then loops over the batch dim (4 iters).
//
// Output stores use explicit `sc1 nt` cache policy (inline asm): SC1 gives
// agent scope (no per-XCD L2 allocation) and NT tells the MALL not to
// retain. Plain __builtin_nontemporal_store (nt only) measurably did NOT
// stop LLC allocation (R2: FETCH_SIZE stayed 64MB). Goal: writes stream
// straight to HBM, leaving the full 256MB Infinity Cache for X (128MB) so
// steady-state replays read X from LLC, not HBM.
__global__ __launch_bounds__(256) void
PositionalEncodingLayer_44633300140770_kernel(const float* __restrict__ X,
                                              float* __restrict__ out) {
    const int t = blockIdx.x * blockDim.x + threadIdx.x;
    // chunks per row = D/4 = 512
    const int s  = t >> 9;          // t / 512
    const int c  = t & 511;         // t % 512
    const int d0 = c << 2;          // starting d index (multiple of 4)

    if (s >= PE_S) return;

    // pair indices i0 = d0/2, i1 = d0/2 + 1
    const float log2_10000 = 13.287712379549449f;
    const float pos = (float)s;
    const float i0 = (float)(d0 >> 1);
    const float i1 = i0 + 1.0f;

    // inv_freq = 10000^(-2i/D) = exp2(-(2i/D)*log2(10000))
    const float inv_f0 = exp2f(-(2.0f * i0 / (float)PE_D) * log2_10000);
    const float inv_f1 = exp2f(-(2.0f * i1 / (float)PE_D) * log2_10000);

    float s0, c0, s1, c1;
    sincosf(pos * inv_f0, &s0, &c0);
    sincosf(pos * inv_f1, &s1, &c1);

    f32x4 pe;
    pe.x = s0; pe.y = c0; pe.z = s1; pe.w = c1;

    const f32x4* __restrict__ X4 = (const f32x4*)X;
    f32x4* __restrict__ O4 = (f32x4*)out;

    const size_t row_chunk = (size_t)s * (PE_D / 4) + (size_t)c;
    const size_t batch_stride = (size_t)PE_S * (PE_D / 4);  // f32x4 units per batch

#pragma unroll
    for (int b = 0; b < PE_B; ++b) {
        const size_t idx = (size_t)b * batch_stride + row_chunk;
        f32x4 x = X4[idx];
        x += pe;
        f32x4* p = O4 + idx;
        // Streaming store: agent scope (SC1) + non-temporal (NT).
        asm volatile("global_store_dwordx4 %0, %1, off sc1 nt"
                     :
                     : "v"(p), "v"(x)
                     : "memory");
    }
}

extern "C" void kernel_launch(void* const* d_in, const int* in_sizes, int n_in,
                              void* d_out, int out_size, void* d_ws, size_t ws_size,
                              hipStream_t stream) {
    (void)in_sizes; (void)n_in; (void)d_ws; (void)ws_size; (void)out_size;
    const float* X = (const float*)d_in[0];
    float* out = (float*)d_out;

    const int total_threads = PE_S * (PE_D / 4);   // 4096 * 512 = 2,097,152
    const int block = 256;
    const int grid = (total_threads + block - 1) / block;  // 8192 blocks

    PositionalEncodingLayer_44633300140770_kernel<<<grid, block, 0, stream>>>(X, out);
}